// Round 1
// baseline (319.465 us; speedup 1.0000x reference)
//
#include <hip/hip_runtime.h>
#include <hip/hip_bf16.h>

typedef __attribute__((ext_vector_type(8))) __bf16 bf16x8;
typedef __attribute__((ext_vector_type(4))) float f32x4;

// ws layout:
//   [0..8)    float acc[2]: acc[0]=denom, acc[1]=sum of pos dots
//   [256..)   unsigned bits[N]
//   [256+4N.) __bf16 out[N*128]   (row-normalized concat, bf16)

__global__ __launch_bounds__(256) void normalize_kernel(
    const float* __restrict__ x, const float* __restrict__ xa,
    __bf16* __restrict__ outb, float* __restrict__ dotacc, int B)
{
    int wave = threadIdx.x >> 6;
    int lane = threadIdx.x & 63;
    int row = blockIdx.x * 4 + wave;
    if (row >= B) return;
    const float2* px = (const float2*)(x  + (size_t)row * 128);
    const float2* pa = (const float2*)(xa + (size_t)row * 128);
    float2 v1 = px[lane];
    float2 v2 = pa[lane];
    float s1 = v1.x * v1.x + v1.y * v1.y;
    float s2 = v2.x * v2.x + v2.y * v2.y;
    float d  = v1.x * v2.x + v1.y * v2.y;
    #pragma unroll
    for (int off = 32; off; off >>= 1) {
        s1 += __shfl_xor(s1, off);
        s2 += __shfl_xor(s2, off);
        d  += __shfl_xor(d,  off);
    }
    float rn1 = rsqrtf(s1);
    float rn2 = rsqrtf(s2);
    __bf16* o1 = outb + (size_t)row * 128;
    __bf16* o2 = outb + (size_t)(B + row) * 128;
    o1[2 * lane]     = (__bf16)(v1.x * rn1);
    o1[2 * lane + 1] = (__bf16)(v1.y * rn1);
    o2[2 * lane]     = (__bf16)(v2.x * rn2);
    o2[2 * lane + 1] = (__bf16)(v2.y * rn2);
    if (lane == 0) atomicAdd(dotacc, d * rn1 * rn2);
}

__global__ __launch_bounds__(256) void bits_kernel(
    const int* __restrict__ nq, unsigned* __restrict__ bits, int N)
{
    int t = blockIdx.x * 256 + threadIdx.x;
    if (t >= N) return;
    const int* p = nq + (size_t)t * 10;
    unsigned b = 0;
    #pragma unroll
    for (int k = 0; k < 10; ++k) b |= 1u << (p[k] & 31);
    bits[t] = b;
}

// One block computes a 128x128 tile of G = out*out^T (upper triangle only),
// applies exp(g*5), masks, and reduces to one atomicAdd.
// LDS tiles are XOR-swizzled at 16B-chunk granularity to kill bank conflicts
// on both the staging writes and the mfma fragment reads (2-way max = free).
__global__ __launch_bounds__(256) void sim_kernel(
    const __bf16* __restrict__ outb, const unsigned* __restrict__ bits,
    const int* __restrict__ hq, float* __restrict__ denom_acc, int N)
{
    int bi = blockIdx.x, bj = blockIdx.y;
    if (bj < bi) return;  // symmetry: e_ij == e_ji; off-diag tiles carry both masks

    __shared__ __bf16 lA[128 * 128];
    __shared__ __bf16 lB[128 * 128];
    __shared__ unsigned sBitsR[128];
    __shared__ unsigned sBitsC[128];
    __shared__ int sHqR[128];
    __shared__ int sHqC[128];
    __shared__ float red[4];

    int tid = threadIdx.x;

    // Stage A (rows bi*128..) and B (rows bj*128..): each is a contiguous
    // 32 KB chunk of outb. 16B per thread per iter, swizzled chunk position.
    const float4* gA = (const float4*)(outb + (size_t)bi * 128 * 128);
    const float4* gB = (const float4*)(outb + (size_t)bj * 128 * 128);
    float4* sA4 = (float4*)lA;
    float4* sB4 = (float4*)lB;
    #pragma unroll
    for (int it = 0; it < 8; ++it) {
        int ci = it * 256 + tid;          // chunk index 0..2047
        int row = ci >> 4;                // 16 chunks (16B each) per row
        int c = ci & 15;
        int pos = c ^ (row & 15);
        sA4[row * 16 + pos] = gA[ci];
        sB4[row * 16 + pos] = gB[ci];
    }
    if (tid < 128) {
        sBitsR[tid] = bits[bi * 128 + tid];
        sHqR[tid]   = hq[bi * 128 + tid];
        sBitsC[tid] = bits[bj * 128 + tid];
        sHqC[tid]   = hq[bj * 128 + tid];
    }
    __syncthreads();

    int wave = tid >> 6, lane = tid & 63;
    int wr = (wave >> 1) * 64;   // wave's 64x64 subtile origin
    int wc = (wave & 1) * 64;
    int lrow = lane & 15, quad = lane >> 4;

    f32x4 acc[4][4] = {};
    #pragma unroll
    for (int kk = 0; kk < 4; ++kk) {     // K=128 in 4 steps of 32
        int chunk = kk * 4 + quad;       // 16B chunk index along k
        bf16x8 a[4], b[4];
        #pragma unroll
        for (int m = 0; m < 4; ++m) {
            int r = wr + m * 16 + lrow;
            a[m] = *(const bf16x8*)&lA[r * 128 + ((chunk ^ (r & 15)) << 3)];
        }
        #pragma unroll
        for (int n = 0; n < 4; ++n) {
            int r = wc + n * 16 + lrow;
            b[n] = *(const bf16x8*)&lB[r * 128 + ((chunk ^ (r & 15)) << 3)];
        }
        #pragma unroll
        for (int m = 0; m < 4; ++m)
            #pragma unroll
            for (int n = 0; n < 4; ++n)
                acc[m][n] = __builtin_amdgcn_mfma_f32_16x16x32_bf16(
                    a[m], b[n], acc[m][n], 0, 0, 0);
    }

    // Epilogue: C/D layout col = lane&15, row = quad*4 + reg.
    float lsum = 0.0f;
    bool diag = (bi == bj);
    #pragma unroll
    for (int m = 0; m < 4; ++m) {
        #pragma unroll
        for (int n = 0; n < 4; ++n) {
            int c_l = wc + n * 16 + lrow;
            unsigned bC = sBitsC[c_l];
            int hC = sHqC[c_l];
            #pragma unroll
            for (int r = 0; r < 4; ++r) {
                int r_l = wr + m * 16 + quad * 4 + r;
                float e = __expf(acc[m][n][r] * 5.0f);
                unsigned w = (sBitsR[r_l] >> hC) & 1u;
                if (diag) {
                    if (r_l == c_l) w = 0;
                } else {
                    w += (bC >> sHqR[r_l]) & 1u;
                }
                lsum += e * (float)w;
            }
        }
    }

    #pragma unroll
    for (int off = 32; off; off >>= 1) lsum += __shfl_down(lsum, off);
    if (lane == 0) red[wave] = lsum;
    __syncthreads();
    if (tid == 0) atomicAdd(denom_acc, red[0] + red[1] + red[2] + red[3]);
}

__global__ void finalize_kernel(const float* __restrict__ acc,
                                float* __restrict__ out, float invB)
{
    out[0] = logf(acc[0]) - 5.0f * acc[1] * invB;
}

extern "C" void kernel_launch(void* const* d_in, const int* in_sizes, int n_in,
                              void* d_out, int out_size, void* d_ws, size_t ws_size,
                              hipStream_t stream) {
    const float* x  = (const float*)d_in[0];
    const float* xa = (const float*)d_in[1];
    const int* hq   = (const int*)d_in[2];
    const int* nq   = (const int*)d_in[3];
    int B = in_sizes[0] / 128;   // 8192
    int N = 2 * B;               // 16384

    char* ws = (char*)d_ws;
    float* acc = (float*)ws;                                   // 2 floats
    unsigned* bits = (unsigned*)(ws + 256);                    // N u32
    __bf16* outb = (__bf16*)(ws + 256 + (size_t)N * 4);        // N*128 bf16

    hipMemsetAsync(acc, 0, 2 * sizeof(float), stream);
    normalize_kernel<<<B / 4, 256, 0, stream>>>(x, xa, outb, acc + 1, B);
    bits_kernel<<<(N + 255) / 256, 256, 0, stream>>>(nq, bits, N);
    dim3 grid(N / 128, N / 128);
    sim_kernel<<<grid, 256, 0, stream>>>(outb, bits, hq, acc, N);
    finalize_kernel<<<1, 1, 0, stream>>>(acc, (float*)d_out, 1.0f / (float)B);
}

// Round 3
// 161.659 us; speedup vs baseline: 1.9762x; 1.9762x over previous
//
#include <hip/hip_runtime.h>
#include <hip/hip_bf16.h>

typedef __attribute__((ext_vector_type(8))) __bf16 bf16x8;
typedef __attribute__((ext_vector_type(4))) float f32x4;

#define SCALE 2.68588886f   // sqrt(5 * log2(e)); acc = 5*log2(e)*cos_sim

static __device__ __forceinline__ float fastexp2(float x) {
#if __has_builtin(__builtin_amdgcn_exp2f)
    return __builtin_amdgcn_exp2f(x);
#else
    return exp2f(x);
#endif
}

// ws layout — EXACTLY the round-1-proven footprint (4,260,096 bytes):
//   [0..256)          float parts[64]: [0..32) denom slots, [32..48) pos slots
//   [256..65792)      unsigned info[N]: bits(0..9) | h<<10
//   [65792..4260096)  __bf16 outb[N*128]  (row-normalized concat, scaled)

__global__ __launch_bounds__(256) void normalize_kernel(
    const float* __restrict__ x, const float* __restrict__ xa,
    __bf16* __restrict__ outb, float* __restrict__ parts, int B)
{
    __shared__ float sdot[4];
    int wave = threadIdx.x >> 6;
    int lane = threadIdx.x & 63;
    int row = blockIdx.x * 4 + wave;
    const float2* px = (const float2*)(x  + (size_t)row * 128);
    const float2* pa = (const float2*)(xa + (size_t)row * 128);
    float2 v1 = px[lane];
    float2 v2 = pa[lane];
    float s1 = v1.x * v1.x + v1.y * v1.y;
    float s2 = v2.x * v2.x + v2.y * v2.y;
    float d  = v1.x * v2.x + v1.y * v2.y;
    #pragma unroll
    for (int off = 32; off; off >>= 1) {
        s1 += __shfl_xor(s1, off);
        s2 += __shfl_xor(s2, off);
        d  += __shfl_xor(d,  off);
    }
    float rn1 = rsqrtf(s1) * SCALE;
    float rn2 = rsqrtf(s2) * SCALE;
    __bf16* o1 = outb + (size_t)row * 128;
    __bf16* o2 = outb + (size_t)(B + row) * 128;
    o1[2 * lane]     = (__bf16)(v1.x * rn1);
    o1[2 * lane + 1] = (__bf16)(v1.y * rn1);
    o2[2 * lane]     = (__bf16)(v2.x * rn2);
    o2[2 * lane + 1] = (__bf16)(v2.y * rn2);
    // pos dot in exact fp32 (unscaled); one atomic per block, spread 16 slots
    if (lane == 0) sdot[wave] = d * rsqrtf(s1) * rsqrtf(s2);
    __syncthreads();
    if (threadIdx.x == 0)
        atomicAdd(parts + 32 + (blockIdx.x & 15),
                  sdot[0] + sdot[1] + sdot[2] + sdot[3]);
}

__global__ __launch_bounds__(256) void info_kernel(
    const int* __restrict__ nq, const int* __restrict__ hq,
    unsigned* __restrict__ info, int N)
{
    int t = blockIdx.x * 256 + threadIdx.x;
    if (t >= N) return;
    const int* p = nq + (size_t)t * 10;
    unsigned b = 0;
    #pragma unroll
    for (int k = 0; k < 10; ++k) b |= 1u << (p[k] & 31);
    info[t] = b | ((unsigned)hq[t] << 10);   // bits(0..9) | h<<10
}

// One block = one upper-triangular 128x128 tile of G = out*out^T.
// exp2(acc) with pre-scaled inputs; mask weight via popcount; 1 atomic/block.
__global__ __launch_bounds__(256, 2) void sim_kernel(
    const __bf16* __restrict__ outb, const unsigned* __restrict__ info,
    float* __restrict__ parts)
{
    // triangular decode: cum(b) = 128b - b(b-1)/2 tiles before tile-row b
    int t = blockIdx.x;
    int bi = (int)(128.5f - sqrtf(128.5f * 128.5f - 2.0f * (float)t));
    if (bi < 0) bi = 0;
    if (bi > 127) bi = 127;
    while (128 * (bi + 1) - ((bi + 1) * bi) / 2 <= t) ++bi;
    while (128 * bi - (bi * (bi - 1)) / 2 > t) --bi;
    int bj = bi + (t - (128 * bi - (bi * (bi - 1)) / 2));

    __shared__ __bf16 lA[128 * 128];
    __shared__ __bf16 lB[128 * 128];
    __shared__ unsigned sMU[128];   // bits_r | onehot(h_r)<<10
    __shared__ unsigned sMV[128];   // onehot(h_c) | bits_c<<10
    __shared__ float red[4];

    int tid = threadIdx.x;

    // Stage A/B tiles (32 KB each, contiguous rows of outb), XOR-swizzled at
    // 16B-chunk granularity: staging writes and frag reads both <=2-way (free).
    const float4* gA = (const float4*)(outb + (size_t)bi * 128 * 128);
    const float4* gB = (const float4*)(outb + (size_t)bj * 128 * 128);
    float4* sA4 = (float4*)lA;
    float4* sB4 = (float4*)lB;
    #pragma unroll
    for (int it = 0; it < 8; ++it) {
        int ci = it * 256 + tid;          // chunk index 0..2047
        int row = ci >> 4;                // 16 x 16B chunks per 256B row
        int c = ci & 15;
        int pos = c ^ (row & 15);
        sA4[row * 16 + pos] = gA[ci];
        sB4[row * 16 + pos] = gB[ci];
    }
    if (tid < 128) {
        unsigned iR = info[bi * 128 + tid];
        unsigned iC = info[bj * 128 + tid];
        sMU[tid] = (iR & 1023u) | (1u << (10 + (iR >> 10)));
        sMV[tid] = (1u << (iC >> 10)) | ((iC & 1023u) << 10);
        // popc(sMU[r] & sMV[c]) = (bits_r>>h_c & 1) + (bits_c>>h_r & 1)
    }
    __syncthreads();

    int wave = tid >> 6, lane = tid & 63;
    int wr = (wave >> 1) * 64;   // wave's 64x64 subtile origin
    int wc = (wave & 1) * 64;
    int lrow = lane & 15, quad = lane >> 4;

    f32x4 acc[4][4] = {};
    #pragma unroll
    for (int kk = 0; kk < 4; ++kk) {     // K=128 in 4 steps of 32
        int chunk = kk * 4 + quad;       // 16B chunk index along k
        bf16x8 a[4], b[4];
        #pragma unroll
        for (int m = 0; m < 4; ++m) {
            int r = wr + m * 16 + lrow;
            a[m] = *(const bf16x8*)&lA[r * 128 + ((chunk ^ (r & 15)) << 3)];
        }
        #pragma unroll
        for (int n = 0; n < 4; ++n) {
            int r = wc + n * 16 + lrow;
            b[n] = *(const bf16x8*)&lB[r * 128 + ((chunk ^ (r & 15)) << 3)];
        }
        #pragma unroll
        for (int m = 0; m < 4; ++m)
            #pragma unroll
            for (int n = 0; n < 4; ++n)
                acc[m][n] = __builtin_amdgcn_mfma_f32_16x16x32_bf16(
                    a[m], b[n], acc[m][n], 0, 0, 0);
    }

    // Hoist masks to registers (C/D layout: col = lane&15, row = quad*4+reg).
    unsigned mv[4], mu[4][4];
    #pragma unroll
    for (int n = 0; n < 4; ++n) mv[n] = sMV[wc + n * 16 + lrow];
    #pragma unroll
    for (int m = 0; m < 4; ++m)
        #pragma unroll
        for (int r = 0; r < 4; ++r) mu[m][r] = sMU[wr + m * 16 + quad * 4 + r];

    float lsum = 0.0f;
    bool diag = (bi == bj);
    #pragma unroll
    for (int m = 0; m < 4; ++m) {
        #pragma unroll
        for (int n = 0; n < 4; ++n) {
            #pragma unroll
            for (int r = 0; r < 4; ++r) {
                float w = (float)__popc(mu[m][r] & mv[n]);
                if (diag && (wr + m * 16 + quad * 4 + r) == (wc + n * 16 + lrow))
                    w = 0.0f;
                lsum += fastexp2(acc[m][n][r]) * w;
            }
        }
    }
    if (diag) lsum *= 0.5f;   // diag tile counts each unordered pair twice

    #pragma unroll
    for (int off = 32; off; off >>= 1) lsum += __shfl_down(lsum, off);
    if (lane == 0) red[wave] = lsum;
    __syncthreads();
    if (tid == 0)
        atomicAdd(parts + (blockIdx.x & 31),
                  red[0] + red[1] + red[2] + red[3]);
}

__global__ void finalize_kernel(const float* __restrict__ parts,
                                float* __restrict__ out, float invB)
{
    int lane = threadIdx.x;   // 64 threads, one wave
    float v = parts[lane];
    float d = (lane < 32) ? v : 0.0f;
    float p = (lane >= 32 && lane < 48) ? v : 0.0f;
    #pragma unroll
    for (int off = 32; off; off >>= 1) {
        d += __shfl_down(d, off);
        p += __shfl_down(p, off);
    }
    if (lane == 0) out[0] = logf(d) - 5.0f * p * invB;
}

extern "C" void kernel_launch(void* const* d_in, const int* in_sizes, int n_in,
                              void* d_out, int out_size, void* d_ws, size_t ws_size,
                              hipStream_t stream) {
    const float* x  = (const float*)d_in[0];
    const float* xa = (const float*)d_in[1];
    const int* hq   = (const int*)d_in[2];
    const int* nq   = (const int*)d_in[3];
    int B = in_sizes[0] / 128;   // 8192
    int N = 2 * B;               // 16384

    char* ws = (char*)d_ws;
    float* parts = (float*)ws;                        // 64 floats
    unsigned* info = (unsigned*)(ws + 256);           // N u32
    __bf16* outb = (__bf16*)(ws + 256 + (size_t)N * 4);  // N*128 bf16

    hipMemsetAsync(parts, 0, 64 * sizeof(float), stream);
    normalize_kernel<<<B / 4, 256, 0, stream>>>(x, xa, outb, parts, B);
    info_kernel<<<(N + 255) / 256, 256, 0, stream>>>(nq, hq, info, N);
    int T = N / 128;                     // 128 tile-rows
    int nblocks = T * (T + 1) / 2;       // 8256 upper-triangular tiles
    sim_kernel<<<nblocks, 256, 0, stream>>>(outb, info, parts);
    finalize_kernel<<<1, 64, 0, stream>>>(parts, (float*)d_out, 1.0f / (float)B);
}

// Round 4
// 124.478 us; speedup vs baseline: 2.5664x; 1.2987x over previous
//
#include <hip/hip_runtime.h>
#include <hip/hip_bf16.h>

typedef __attribute__((ext_vector_type(8))) __bf16 bf16x8;
typedef __attribute__((ext_vector_type(4))) float f32x4;

#define SCALE 2.68588886f   // sqrt(5 * log2(e)); acc = 5*log2(e)*cos_sim

static __device__ __forceinline__ float fastexp2(float x) {
#if __has_builtin(__builtin_amdgcn_exp2f)
    return __builtin_amdgcn_exp2f(x);
#else
    return exp2f(x);
#endif
}

// ws layout (total 4,235,520 B — inside the round-1-proven 4,260,096 extent):
//   [0..33024)         float denom_parts[8256]   (one slot per sim block)
//   [33024..41216)     float pos_parts[2048]     (one slot per normalize block)
//   [41216..4235520)   __bf16 outb[16384*128]    (normalized concat, scaled)
// No atomics anywhere: every slot is written by exactly one block.

__global__ __launch_bounds__(256) void normalize_kernel(
    const float* __restrict__ x, const float* __restrict__ xa,
    __bf16* __restrict__ outb, float* __restrict__ pos_parts, int B)
{
    __shared__ float sdot[4];
    int wave = threadIdx.x >> 6;
    int lane = threadIdx.x & 63;
    int row = blockIdx.x * 4 + wave;
    const float2* px = (const float2*)(x  + (size_t)row * 128);
    const float2* pa = (const float2*)(xa + (size_t)row * 128);
    float2 v1 = px[lane];
    float2 v2 = pa[lane];
    float s1 = v1.x * v1.x + v1.y * v1.y;
    float s2 = v2.x * v2.x + v2.y * v2.y;
    float d  = v1.x * v2.x + v1.y * v2.y;
    #pragma unroll
    for (int off = 32; off; off >>= 1) {
        s1 += __shfl_xor(s1, off);
        s2 += __shfl_xor(s2, off);
        d  += __shfl_xor(d,  off);
    }
    float rn1 = rsqrtf(s1) * SCALE;
    float rn2 = rsqrtf(s2) * SCALE;
    __bf16* o1 = outb + (size_t)row * 128;
    __bf16* o2 = outb + (size_t)(B + row) * 128;
    o1[2 * lane]     = (__bf16)(v1.x * rn1);
    o1[2 * lane + 1] = (__bf16)(v1.y * rn1);
    o2[2 * lane]     = (__bf16)(v2.x * rn2);
    o2[2 * lane + 1] = (__bf16)(v2.y * rn2);
    if (lane == 0) sdot[wave] = d * rsqrtf(s1) * rsqrtf(s2);  // exact fp32 pos dot
    __syncthreads();
    if (threadIdx.x == 0)
        pos_parts[blockIdx.x] = sdot[0] + sdot[1] + sdot[2] + sdot[3];
}

// One block = one upper-triangular 128x128 tile of G = out*out^T.
// K-split staging: two 128x64 half-tiles (32 KB LDS) -> 4 blocks/CU.
// exp2(acc) with pre-scaled inputs; mask weight via popcount; no atomics.
__global__ __launch_bounds__(256, 4) void sim_kernel(
    const __bf16* __restrict__ outb, const int* __restrict__ hq,
    const int* __restrict__ nq, float* __restrict__ denom_parts)
{
    // triangular decode: cum(b) = 128b - b(b-1)/2 tiles before tile-row b
    int t = blockIdx.x;
    int bi = (int)(128.5f - sqrtf(128.5f * 128.5f - 2.0f * (float)t));
    if (bi < 0) bi = 0;
    if (bi > 127) bi = 127;
    while (128 * (bi + 1) - ((bi + 1) * bi) / 2 <= t) ++bi;
    while (128 * bi - (bi * (bi - 1)) / 2 > t) --bi;
    int bj = bi + (t - (128 * bi - (bi * (bi - 1)) / 2));

    __shared__ __bf16 lA[128 * 64];
    __shared__ __bf16 lB[128 * 64];
    __shared__ unsigned sMU[128];   // bits_r | onehot(h_r)<<10
    __shared__ unsigned sMV[128];   // onehot(h_c) | bits_c<<10
    __shared__ float red[4];

    int tid = threadIdx.x;

    // Build masks directly from nq/hq (L2-hot): 128 threads rows, 128 cols.
    {
        int half = tid >> 7;
        int idx = tid & 127;
        int row = (half ? bj : bi) * 128 + idx;
        const int* p = nq + (size_t)row * 10;
        unsigned b = 0;
        #pragma unroll
        for (int k = 0; k < 10; ++k) b |= 1u << (p[k] & 31);
        unsigned h = (unsigned)hq[row];
        if (half) sMV[idx] = (1u << h) | (b << 10);
        else      sMU[idx] = b | (1u << (10 + h));
        // popc(sMU[r] & sMV[c]) = (bits_r>>h_c & 1) + (bits_c>>h_r & 1)
    }

    const float4* gA = (const float4*)(outb + (size_t)bi * 128 * 128);
    const float4* gB = (const float4*)(outb + (size_t)bj * 128 * 128);
    float4* sA4 = (float4*)lA;
    float4* sB4 = (float4*)lB;

    int wave = tid >> 6, lane = tid & 63;
    int wr = (wave >> 1) * 64;   // wave's 64x64 subtile origin
    int wc = (wave & 1) * 64;
    int lrow = lane & 15, quad = lane >> 4;

    f32x4 acc[4][4] = {};

    #pragma unroll
    for (int ph = 0; ph < 2; ++ph) {
        if (ph) __syncthreads();   // all reads of previous half done
        // Stage half-tiles: 1024 chunks (16B) each of A and B; 8 chunks/row,
        // swizzled pos = c ^ (row&7): writes and frag reads conflict-free.
        #pragma unroll
        for (int it = 0; it < 4; ++it) {
            int ci = it * 256 + tid;
            int row = ci >> 3;
            int c = ci & 7;
            int pos = c ^ (row & 7);
            sA4[row * 8 + pos] = gA[row * 16 + ph * 8 + c];
            sB4[row * 8 + pos] = gB[row * 16 + ph * 8 + c];
        }
        __syncthreads();
        #pragma unroll
        for (int kk = 0; kk < 2; ++kk) {
            int chunk = kk * 4 + quad;       // local 16B chunk along k (0..7)
            bf16x8 a[4], b[4];
            #pragma unroll
            for (int m = 0; m < 4; ++m) {
                int r = wr + m * 16 + lrow;
                a[m] = *(const bf16x8*)&lA[r * 64 + ((chunk ^ (r & 7)) << 3)];
            }
            #pragma unroll
            for (int n = 0; n < 4; ++n) {
                int r = wc + n * 16 + lrow;
                b[n] = *(const bf16x8*)&lB[r * 64 + ((chunk ^ (r & 7)) << 3)];
            }
            #pragma unroll
            for (int m = 0; m < 4; ++m)
                #pragma unroll
                for (int n = 0; n < 4; ++n)
                    acc[m][n] = __builtin_amdgcn_mfma_f32_16x16x32_bf16(
                        a[m], b[n], acc[m][n], 0, 0, 0);
        }
    }

    // Hoist masks to registers (C/D layout: col = lane&15, row = quad*4+reg).
    unsigned mv[4], mu[4][4];
    #pragma unroll
    for (int n = 0; n < 4; ++n) mv[n] = sMV[wc + n * 16 + lrow];
    #pragma unroll
    for (int m = 0; m < 4; ++m)
        #pragma unroll
        for (int r = 0; r < 4; ++r) mu[m][r] = sMU[wr + m * 16 + quad * 4 + r];

    float ls[4] = {0.0f, 0.0f, 0.0f, 0.0f};   // 4 chains: break fmac latency
    bool diag = (bi == bj);
    #pragma unroll
    for (int m = 0; m < 4; ++m) {
        #pragma unroll
        for (int n = 0; n < 4; ++n) {
            #pragma unroll
            for (int r = 0; r < 4; ++r) {
                float w = (float)__popc(mu[m][r] & mv[n]);
                if (diag && (wr + m * 16 + quad * 4 + r) == (wc + n * 16 + lrow))
                    w = 0.0f;
                ls[r] += fastexp2(acc[m][n][r]) * w;
            }
        }
    }
    float lsum = (ls[0] + ls[1]) + (ls[2] + ls[3]);
    if (diag) lsum *= 0.5f;   // diag tile counts each unordered pair twice

    #pragma unroll
    for (int off = 32; off; off >>= 1) lsum += __shfl_down(lsum, off);
    if (lane == 0) red[wave] = lsum;
    __syncthreads();
    if (tid == 0)
        denom_parts[blockIdx.x] = red[0] + red[1] + red[2] + red[3];
}

__global__ __launch_bounds__(1024) void finalize_kernel(
    const float* __restrict__ denom_parts, const float* __restrict__ pos_parts,
    float* __restrict__ out, float invB, int nd, int np)
{
    __shared__ float sred[32];
    int tid = threadIdx.x;
    float d = 0.0f, p = 0.0f;
    for (int i = tid; i < nd; i += 1024) d += denom_parts[i];
    for (int i = tid; i < np; i += 1024) p += pos_parts[i];
    #pragma unroll
    for (int off = 32; off; off >>= 1) {
        d += __shfl_down(d, off);
        p += __shfl_down(p, off);
    }
    int wv = tid >> 6, ln = tid & 63;
    if (ln == 0) { sred[wv] = d; sred[16 + wv] = p; }
    __syncthreads();
    if (tid == 0) {
        float D = 0.0f, P = 0.0f;
        #pragma unroll
        for (int i = 0; i < 16; ++i) { D += sred[i]; P += sred[16 + i]; }
        out[0] = logf(D) - 5.0f * P * invB;
    }
}

extern "C" void kernel_launch(void* const* d_in, const int* in_sizes, int n_in,
                              void* d_out, int out_size, void* d_ws, size_t ws_size,
                              hipStream_t stream) {
    const float* x  = (const float*)d_in[0];
    const float* xa = (const float*)d_in[1];
    const int* hq   = (const int*)d_in[2];
    const int* nq   = (const int*)d_in[3];
    int B = in_sizes[0] / 128;   // 8192
    int N = 2 * B;               // 16384
    int T = N / 128;             // 128 tile-rows
    int nblocks = T * (T + 1) / 2;   // 8256 upper-triangular tiles

    char* ws = (char*)d_ws;
    float* denom_parts = (float*)ws;                       // 8256 f32
    float* pos_parts   = (float*)(ws + 33024);             // 2048 f32
    __bf16* outb       = (__bf16*)(ws + 41216);            // N*128 bf16

    normalize_kernel<<<B / 4, 256, 0, stream>>>(x, xa, outb, pos_parts, B);
    sim_kernel<<<nblocks, 256, 0, stream>>>(outb, hq, nq, denom_parts);
    finalize_kernel<<<1, 1024, 0, stream>>>(denom_parts, pos_parts,
                                            (float*)d_out, 1.0f / (float)B,
                                            nblocks, B / 4);
}